// Round 1
// 63.342 us; speedup vs baseline: 1.0304x; 1.0304x over previous
//
#include <hip/hip_runtime.h>
#include <stdint.h>

#define NROWS 8192
#define FDIM  256   // K (feature dim)
#define DDIM  64    // N (out dim)

typedef __attribute__((ext_vector_type(8))) short short8;   // 8 bf16 = 4 VGPR (MFMA A/B frag)
typedef __attribute__((ext_vector_type(4))) float floatx4;  // MFMA C/D frag

// Pack two fp32 -> bf16x2, round-to-nearest-even (inputs finite; no NaN path needed).
__device__ inline unsigned int pack2_bf16(float a, float b) {
    unsigned int ua = __float_as_uint(a);
    unsigned int ub = __float_as_uint(b);
    ua += 0x7fffu + ((ua >> 16) & 1u);
    ub += 0x7fffu + ((ub >> 16) & 1u);
    return (ua >> 16) | (ub & 0xffff0000u);
}

// ---------------------------------------------------------------------------
// Prep kernel: runs every iteration (ws is re-poisoned by the harness), but
// dedups what the old kernel did redundantly in all 256 blocks:
//   blocks 0..7  : pack W[256][64] into 2048 frag-ready bf16x8 frags in ws.
//                  Frag f = ks*256 + nt*64 + lane holds
//                  W[ks*32 + (lane>>4)*8 + j][nt*16 + (lane&15)], j=0..7
//                  (B-layout for mfma_f32_16x16x32_bf16, verified in prior kernel).
//   blocks 8..11 : bias partial colsums -> ws[32768 + blk64 + c] (4 x 64 fp32).
// ws layout: [0, 32768) W frags; [32768, 33792) bias partials.
// ---------------------------------------------------------------------------
__global__ __launch_bounds__(256)
void nanembed_prep(const float* __restrict__ W, const float* __restrict__ b,
                   unsigned int* __restrict__ ws)
{
    const int t   = threadIdx.x;
    const int blk = blockIdx.x;
    if (blk < 8) {
        // One frag per thread: 8 strided W loads (64 KB total across 8 blocks,
        // 16-lane-coalesced 64B segments), 4 pack2, 1 dwordx4 store.
        const int f  = blk * 256 + t;          // 0..2047
        const int ks = f >> 8;
        const int fl = f & 63;
        const int c  = ((f >> 6) & 3) * 16 + (fl & 15);
        const float* wp = W + (size_t)(ks * 32 + (fl >> 4) * 8) * DDIM + c;
        union { short8 s; unsigned int u[4]; } fr;
        fr.u[0] = pack2_bf16(wp[0 * DDIM], wp[1 * DDIM]);
        fr.u[1] = pack2_bf16(wp[2 * DDIM], wp[3 * DDIM]);
        fr.u[2] = pack2_bf16(wp[4 * DDIM], wp[5 * DDIM]);
        fr.u[3] = pack2_bf16(wp[6 * DDIM], wp[7 * DDIM]);
        reinterpret_cast<short8*>(ws)[f] = fr.s;
    } else {
        // Bias colsum over f-range [(blk-8)*64, +64), 16 KB coalesced loads/block.
        __shared__ float part[4][64];
        const int c     = t & 63;
        const int seg   = t >> 6;
        const int fbase = (blk - 8) * 64 + seg * 16;
        float s = 0.f;
        #pragma unroll
        for (int i = 0; i < 16; ++i)
            s += b[(size_t)(fbase + i) * DDIM + c];
        part[seg][c] = s;
        __syncthreads();
        if (t < 64) {
            reinterpret_cast<float*>(ws)[8192 + (blk - 8) * 64 + t] =
                part[0][t] + part[1][t] + part[2][t] + part[3][t];
        }
    }
}

// ---------------------------------------------------------------------------
// Main kernel: grid 512 x 128 (2 blocks/CU, 4 waves/CU). Block = 16 rows.
// The 2 waves split K: wave wk handles k in [wk*128, wk*128+128) -> 4 k-steps
// x 4 n-tiles = 16 MFMAs/wave. B-frags load straight from L2-hot ws (fully
// coalesced dwordx4, no re-pack, no LDS staging, no pre-MFMA barrier). The two
// K-halves are merged through a 4 KB LDS reduction.
// Layouts (verified in prior kernel):
//   A[m=lane&15][k=(lane>>4)*8+j]   (x rows, packed from regs)
//   D col=lane&15, row=(lane>>4)*4+reg
// ---------------------------------------------------------------------------
__global__ __launch_bounds__(128)
void nanembed_main(const float* __restrict__ x,
                   const unsigned int* __restrict__ ws,
                   float* __restrict__ out)
{
    __shared__ floatx4 red[4][64];   // 4 KB: wk=1 partial accs

    const int tid  = threadIdx.x;    // 0..127
    const int lane = tid & 63;
    const int wk   = tid >> 6;       // K-half 0/1
    const int q    = lane >> 4;      // quad 0..3
    const int n    = lane & 15;
    const int r0   = blockIdx.x * 16;

    // ---- 1) x loads first (the only HBM-cold read): row r0+n,
    //         cols wk*128 + ks*32 + q*8 + [0,8) -> 8 dwordx4 in flight.
    const float4* xp = reinterpret_cast<const float4*>(x + (size_t)(r0 + n) * FDIM)
                       + (wk * 32 + q * 2);
    float4 xv[8];
    #pragma unroll
    for (int ks = 0; ks < 4; ++ks) {
        xv[2 * ks]     = xp[ks * 8];
        xv[2 * ks + 1] = xp[ks * 8 + 1];
    }

    // ---- 2) B-frags direct from ws (L2-hot 32 KB shared by all blocks):
    //         16 coalesced dwordx4 loads, consecutive lanes -> consecutive 16B.
    const short8* wf = reinterpret_cast<const short8*>(ws);
    short8 bf[4][4];
    #pragma unroll
    for (int ks = 0; ks < 4; ++ks)
        #pragma unroll
        for (int nt = 0; nt < 4; ++nt)
            bf[ks][nt] = wf[(wk * 4 + ks) * 256 + nt * 64 + lane];

    // ---- 3) MFMA loop: pack A from regs, 4 ks x 4 nt.
    floatx4 acc[4] = {{0.f, 0.f, 0.f, 0.f}, {0.f, 0.f, 0.f, 0.f},
                      {0.f, 0.f, 0.f, 0.f}, {0.f, 0.f, 0.f, 0.f}};
    #pragma unroll
    for (int ks = 0; ks < 4; ++ks) {
        union { short8 s; unsigned int u[4]; } fa;
        float4 v0 = xv[2 * ks], v1 = xv[2 * ks + 1];
        fa.u[0] = pack2_bf16(v0.x, v0.y);
        fa.u[1] = pack2_bf16(v0.z, v0.w);
        fa.u[2] = pack2_bf16(v1.x, v1.y);
        fa.u[3] = pack2_bf16(v1.z, v1.w);
        #pragma unroll
        for (int nt = 0; nt < 4; ++nt)
            acc[nt] = __builtin_amdgcn_mfma_f32_16x16x32_bf16(fa.s, bf[ks][nt], acc[nt], 0, 0, 0);
    }

    // ---- 4) Cross-wave K-reduction: wk=1 writes 4x ds_write_b128
    //         (lanes stride 16B -> conflict-free), wk=0 merges.
    if (wk == 1) {
        #pragma unroll
        for (int nt = 0; nt < 4; ++nt)
            red[nt][lane] = acc[nt];
    }
    __syncthreads();

    // ---- 5) Epilogue (wk=0 only): + other K-half + exact fp32 bias colsum
    //         (4 partials from prep), scale 1/256, 16 dword stores.
    if (wk == 0) {
        const float* pc = reinterpret_cast<const float*>(ws) + 8192;
        #pragma unroll
        for (int nt = 0; nt < 4; ++nt) {
            floatx4 o = red[nt][lane];
            const int c = nt * 16 + n;
            const float bs = pc[c] + pc[64 + c] + pc[128 + c] + pc[192 + c];
            #pragma unroll
            for (int reg = 0; reg < 4; ++reg) {
                const int r = r0 + q * 4 + reg;
                out[(size_t)r * DDIM + c] = (acc[nt][reg] + o[reg] + bs) * (1.0f / 256.0f);
            }
        }
    }
}

extern "C" void kernel_launch(void* const* d_in, const int* in_sizes, int n_in,
                              void* d_out, int out_size, void* d_ws, size_t ws_size,
                              hipStream_t stream) {
    const float* x = (const float*)d_in[0];   // [8192, 256]
    const float* W = (const float*)d_in[1];   // [256, 64]
    const float* b = (const float*)d_in[2];   // [256, 64]
    float* out = (float*)d_out;               // [8192, 64]
    unsigned int* ws = (unsigned int*)d_ws;   // >= 33 KB used

    // ws is re-poisoned by the harness each iteration -> prep must run in-graph.
    nanembed_prep<<<dim3(12), 256, 0, stream>>>(W, b, ws);
    nanembed_main<<<dim3(512), 128, 0, stream>>>(x, ws, out);
}